// Round 11
// baseline (856.788 us; speedup 1.0000x reference)
//
#include <hip/hip_runtime.h>

#define HD 128
#define EMB 64
#define EPS 1e-5f

typedef __bf16 bf16x8 __attribute__((ext_vector_type(8)));
typedef float f32x4 __attribute__((ext_vector_type(4)));

__device__ __forceinline__ float4 ld4(const float* p) {
    return *reinterpret_cast<const float4*>(p);
}

// float -> bf16 with round-to-nearest-even
__device__ __forceinline__ unsigned short f2bf(float f) {
    unsigned u = __float_as_uint(f);
    u += 0x7FFF + ((u >> 16) & 1);
    return (unsigned short)(u >> 16);
}
// bf16 pair unpack from packed u32 (elem0 = low 16 bits)
__device__ __forceinline__ float blo(unsigned u) { return __uint_as_float(u << 16); }
__device__ __forceinline__ float bhi(unsigned u) { return __uint_as_float(u & 0xffff0000u); }
__device__ __forceinline__ unsigned pk2(float a, float b) {
    return (unsigned)f2bf(a) | ((unsigned)f2bf(b) << 16);
}

// ---------------- degree histogram ----------------
__global__ void k_hist(const int* __restrict__ dst, int* __restrict__ deg, int e) {
    int i = blockIdx.x * blockDim.x + threadIdx.x;
    if (i < e) atomicAdd(&deg[dst[i]], 1);
}

__global__ void k_dinv(const int* __restrict__ deg, float* __restrict__ dinv, int n) {
    int i = blockIdx.x * blockDim.x + threadIdx.x;
    if (i < n) dinv[i] = 1.0f / sqrtf((float)deg[i] + 1.0f);
}

// ---------------- exclusive scan (3-phase) ----------------
__global__ void k_scan_part(const int* __restrict__ deg, int* __restrict__ out,
                            int* __restrict__ bsum, int n) {
    __shared__ int s[256];
    int i = blockIdx.x * 256 + threadIdx.x;
    int v = (i < n) ? deg[i] : 0;
    s[threadIdx.x] = v;
    __syncthreads();
    #pragma unroll
    for (int off = 1; off < 256; off <<= 1) {
        int t = (threadIdx.x >= off) ? s[threadIdx.x - off] : 0;
        __syncthreads();
        s[threadIdx.x] += t;
        __syncthreads();
    }
    if (i < n) out[i] = s[threadIdx.x] - v;         // exclusive
    if (threadIdx.x == 255) bsum[blockIdx.x] = s[255];
}

__global__ void k_scan_mid(int* __restrict__ bsum, int nb) {
    __shared__ int s[512];
    int t = threadIdx.x;
    int v = (t < nb) ? bsum[t] : 0;
    s[t] = v;
    __syncthreads();
    for (int off = 1; off < 512; off <<= 1) {
        int u = (t >= off) ? s[t - off] : 0;
        __syncthreads();
        s[t] += u;
        __syncthreads();
    }
    if (t < nb) bsum[t] = s[t] - v;                 // exclusive block offsets
}

// also fills the scatter cursor (saves a d2d memcpy dispatch)
__global__ void k_scan_add(int* __restrict__ rs, int* __restrict__ cursor,
                           const int* __restrict__ bsum, int n, int e_total) {
    int i = blockIdx.x * 256 + threadIdx.x;
    if (i < n) {
        int v = rs[i] + bsum[blockIdx.x];
        rs[i] = v;
        cursor[i] = v;
    }
    if (i == 0) rs[n] = e_total;
}

// ---------------- CSR scatter ----------------
__global__ void k_scatter(const int* __restrict__ src, const int* __restrict__ dst,
                          int* __restrict__ cursor, int* __restrict__ csr_src, int e) {
    int i = blockIdx.x * blockDim.x + threadIdx.x;
    if (i < e) {
        int d = dst[i];
        int pos = atomicAdd(&cursor[d], 1);
        csr_src[pos] = src[i];
    }
}

// ---------------- weight prep: Wt[m][n][k] = bf16(Wsrc[m][k][n]) ----------------
__global__ void k_wprep(const float* __restrict__ W_in, const float* __restrict__ Ws,
                        unsigned short* __restrict__ wt) {
    int m = blockIdx.x >> 7;
    int nn = blockIdx.x & 127;
    int k = threadIdx.x;
    const float* src = (m == 0) ? W_in : Ws + (size_t)(m - 1) * 16384;
    wt[(size_t)m * 16384 + nn * 128 + k] = f2bf(src[k * 128 + nn]);
}

// ---------------- bf16 MFMA GEMM v2: C[M,128] = act(A[M,128]) @ W[128,128] ------------
// 128 rows/block, sA only in LDS (32KB, swizzled); W-fragments read direct from
// L2-resident Wt. BN coefficients computed in-kernel from per-layer colsum stats.
template <bool APPLY_BN, bool OUT_BIAS_RELU, bool OUT_BF16>
__global__ __launch_bounds__(256) void k_gemm(
        const float* __restrict__ A, const unsigned short* __restrict__ Wt,
        const float* __restrict__ bias,
        const float* __restrict__ gamma, const float* __restrict__ beta,
        const float* __restrict__ colsum, const float* __restrict__ colsumsq,
        float inv_n, void* __restrict__ Cout, int M) {
    __shared__ char sA[128 * 256];   // 128 rows x 128 bf16 (swizzled)
    __shared__ float s_affa[HD], s_affb[HD];
    const int tid = threadIdx.x;
    const int row0 = blockIdx.x * 128;

    if (APPLY_BN) {
        if (tid < HD) {
            float mean = colsum[tid] * inv_n;
            float var = colsumsq[tid] * inv_n - mean * mean;
            float rstd = 1.0f / sqrtf(var + EPS);
            float a = gamma[tid] * rstd;
            s_affa[tid] = a;
            s_affb[tid] = beta[tid] - mean * a;
        }
        __syncthreads();
    }

    // stage A -> sA: fp32 load, optional BN+relu, bf16 convert, swizzled store
    #pragma unroll
    for (int it = 0; it < 8; ++it) {
        int idx = it * 256 + tid;            // 16B chunk id, 0..2047
        int r = idx >> 4, c = idx & 15;      // row, 8-col chunk
        int gm = row0 + r;
        float4 v0 = make_float4(0.f, 0.f, 0.f, 0.f), v1 = v0;
        if (gm < M) {
            v0 = ld4(A + (size_t)gm * HD + c * 8);
            v1 = ld4(A + (size_t)gm * HD + c * 8 + 4);
        }
        if (APPLY_BN) {
            int f0 = c * 8;
            v0.x = fmaxf(fmaf(v0.x, s_affa[f0 + 0], s_affb[f0 + 0]), 0.f);
            v0.y = fmaxf(fmaf(v0.y, s_affa[f0 + 1], s_affb[f0 + 1]), 0.f);
            v0.z = fmaxf(fmaf(v0.z, s_affa[f0 + 2], s_affb[f0 + 2]), 0.f);
            v0.w = fmaxf(fmaf(v0.w, s_affa[f0 + 3], s_affb[f0 + 3]), 0.f);
            v1.x = fmaxf(fmaf(v1.x, s_affa[f0 + 4], s_affb[f0 + 4]), 0.f);
            v1.y = fmaxf(fmaf(v1.y, s_affa[f0 + 5], s_affb[f0 + 5]), 0.f);
            v1.z = fmaxf(fmaf(v1.z, s_affa[f0 + 6], s_affb[f0 + 6]), 0.f);
            v1.w = fmaxf(fmaf(v1.w, s_affa[f0 + 7], s_affb[f0 + 7]), 0.f);
        }
        uint4 pk;
        pk.x = pk2(v0.x, v0.y); pk.y = pk2(v0.z, v0.w);
        pk.z = pk2(v1.x, v1.y); pk.w = pk2(v1.z, v1.w);
        int byte = r * 256 + c * 16;
        *reinterpret_cast<uint4*>(sA + (byte ^ ((r & 7) << 4))) = pk;
    }
    __syncthreads();

    const int wave = tid >> 6;
    const int lane = tid & 63;
    const int l15 = lane & 15;
    const int kq  = lane >> 4;               // k-quarter within K=32 step

    // hoist A fragments: 2 m-tiles x 4 K-steps per wave (32 rows/wave)
    bf16x8 af[2][4];
    #pragma unroll
    for (int mt = 0; mt < 2; ++mt) {
        int arow = wave * 32 + mt * 16 + l15;
        int base = arow * 256;
        int sw = (arow & 7) << 4;
        #pragma unroll
        for (int ks = 0; ks < 4; ++ks) {
            int byte = base + kq * 16 + ks * 64;
            af[mt][ks] = __builtin_bit_cast(bf16x8,
                *reinterpret_cast<const uint4*>(sA + (byte ^ sw)));
        }
    }

    const uint4* __restrict__ Wt4 = (const uint4*)Wt;   // row = 16 x uint4
    #pragma unroll
    for (int nt = 0; nt < 8; ++nt) {
        int wrow = nt * 16 + l15;
        f32x4 c0 = {0.f, 0.f, 0.f, 0.f};
        f32x4 c1 = {0.f, 0.f, 0.f, 0.f};
        #pragma unroll
        for (int ks = 0; ks < 4; ++ks) {
            bf16x8 bf = __builtin_bit_cast(bf16x8, Wt4[wrow * 16 + ks * 4 + kq]);
            c0 = __builtin_amdgcn_mfma_f32_16x16x32_bf16(af[0][ks], bf, c0, 0, 0, 0);
            c1 = __builtin_amdgcn_mfma_f32_16x16x32_bf16(af[1][ks], bf, c1, 0, 0, 0);
        }
        // C layout: col = lane&15, row = (lane>>4)*4 + i   [m89 verified]
        int col = nt * 16 + l15;
        #pragma unroll
        for (int mt = 0; mt < 2; ++mt) {
            f32x4 c = mt ? c1 : c0;
            int grbase = row0 + wave * 32 + mt * 16 + kq * 4;
            if (OUT_BF16) {
                unsigned short* C16 = (unsigned short*)Cout;
                #pragma unroll
                for (int i = 0; i < 4; ++i) {
                    int gr = grbase + i;
                    if (gr < M) C16[(size_t)gr * HD + col] = f2bf(c[i]);
                }
            } else {
                float* C32 = (float*)Cout;
                float bb = OUT_BIAS_RELU ? bias[col] : 0.f;
                #pragma unroll
                for (int i = 0; i < 4; ++i) {
                    int gr = grbase + i;
                    float o = c[i];
                    if (OUT_BIAS_RELU) o = fmaxf(o + bb, 0.f);
                    if (gr < M) C32[(size_t)gr * HD + col] = o;
                }
            }
        }
    }
}

// ---------------- per-node aggregation + BN stats (4 edges per gather instr) ----------
#define NPB 8
__global__ void k_agg(const unsigned short* __restrict__ hw, const int* __restrict__ row_start,
                      const int* __restrict__ csr_src, const float* __restrict__ dinv,
                      const float* __restrict__ bias_row, float* __restrict__ h_pre,
                      float* __restrict__ colsum, float* __restrict__ colsumsq, int n) {
    const int tid  = threadIdx.x;
    const int lane = tid & 63;
    const int slot = tid >> 6;       // wave id 0..3
    const int q    = lane & 15;      // 16B slice (features q*8 .. q*8+7)
    const int grp  = lane >> 4;      // edge group 0..3
    const int n0 = blockIdx.x * (4 * NPB);
    const uint4* __restrict__ hw4 = (const uint4*)hw;   // row = 16 x uint4

    float b8[8];
    #pragma unroll
    for (int k = 0; k < 8; ++k) b8[k] = bias_row[q * 8 + k];

    float psum8[8], psq8[8];
    #pragma unroll
    for (int k = 0; k < 8; ++k) { psum8[k] = 0.f; psq8[k] = 0.f; }

    for (int nn = 0; nn < NPB; ++nn) {
        int node = n0 + nn * 4 + slot;     // wave-uniform
        if (node >= n) continue;
        float dn = dinv[node];
        float acc[8];
        #pragma unroll
        for (int k = 0; k < 8; ++k) acc[k] = 0.f;

        const int jb = row_start[node], je = row_start[node + 1];
        for (int j = jb; j < je; j += 8) {
            int e0 = j + grp;
            int s0 = (e0 < je) ? csr_src[e0] : 0;
            float w0 = (e0 < je) ? dinv[s0] * dn : 0.f;
            uint4 r0 = hw4[(size_t)s0 * 16 + q];
            int e1 = j + 4 + grp;
            int s1 = (e1 < je) ? csr_src[e1] : 0;
            float w1 = (e1 < je) ? dinv[s1] * dn : 0.f;
            uint4 r1 = hw4[(size_t)s1 * 16 + q];

            acc[0] = fmaf(blo(r0.x), w0, acc[0]); acc[1] = fmaf(bhi(r0.x), w0, acc[1]);
            acc[2] = fmaf(blo(r0.y), w0, acc[2]); acc[3] = fmaf(bhi(r0.y), w0, acc[3]);
            acc[4] = fmaf(blo(r0.z), w0, acc[4]); acc[5] = fmaf(bhi(r0.z), w0, acc[5]);
            acc[6] = fmaf(blo(r0.w), w0, acc[6]); acc[7] = fmaf(bhi(r0.w), w0, acc[7]);

            acc[0] = fmaf(blo(r1.x), w1, acc[0]); acc[1] = fmaf(bhi(r1.x), w1, acc[1]);
            acc[2] = fmaf(blo(r1.y), w1, acc[2]); acc[3] = fmaf(bhi(r1.y), w1, acc[3]);
            acc[4] = fmaf(blo(r1.z), w1, acc[4]); acc[5] = fmaf(bhi(r1.z), w1, acc[5]);
            acc[6] = fmaf(blo(r1.w), w1, acc[6]); acc[7] = fmaf(bhi(r1.w), w1, acc[7]);
        }

        #pragma unroll
        for (int k = 0; k < 8; ++k) acc[k] += __shfl_xor(acc[k], 16, 64);
        #pragma unroll
        for (int k = 0; k < 8; ++k) acc[k] += __shfl_xor(acc[k], 32, 64);

        uint4 ow = hw4[(size_t)node * 16 + q];
        float sn = dn * dn;
        acc[0] = fmaf(blo(ow.x), sn, acc[0] + b8[0]);
        acc[1] = fmaf(bhi(ow.x), sn, acc[1] + b8[1]);
        acc[2] = fmaf(blo(ow.y), sn, acc[2] + b8[2]);
        acc[3] = fmaf(bhi(ow.y), sn, acc[3] + b8[3]);
        acc[4] = fmaf(blo(ow.z), sn, acc[4] + b8[4]);
        acc[5] = fmaf(bhi(ow.z), sn, acc[5] + b8[5]);
        acc[6] = fmaf(blo(ow.w), sn, acc[6] + b8[6]);
        acc[7] = fmaf(bhi(ow.w), sn, acc[7] + b8[7]);

        if (grp == 0) {
            float* dst = h_pre + (size_t)node * HD + q * 8;
            *reinterpret_cast<float4*>(dst)     = make_float4(acc[0], acc[1], acc[2], acc[3]);
            *reinterpret_cast<float4*>(dst + 4) = make_float4(acc[4], acc[5], acc[6], acc[7]);
            #pragma unroll
            for (int k = 0; k < 8; ++k) {
                psum8[k] += acc[k];
                psq8[k] = fmaf(acc[k], acc[k], psq8[k]);
            }
        }
    }

    __shared__ float redS[4][128];
    __shared__ float redQ[4][128];
    if (grp == 0) {
        #pragma unroll
        for (int k = 0; k < 8; ++k) {
            redS[slot][q * 8 + k] = psum8[k];
            redQ[slot][q * 8 + k] = psq8[k];
        }
    }
    __syncthreads();
    int f = tid & 127;
    if (tid < 128) {
        float s = redS[0][f] + redS[1][f] + redS[2][f] + redS[3][f];
        atomicAdd(&colsum[f], s);
    } else {
        float s = redQ[0][f] + redQ[1][f] + redQ[2][f] + redQ[3][f];
        atomicAdd(&colsumsq[f], s);
    }
}

// ---------------- graph boundaries (batch sorted) ----------------
__global__ void k_gbounds(const int* __restrict__ batch, int* __restrict__ gstart,
                          int n, int g) {
    int gi = blockIdx.x * blockDim.x + threadIdx.x;
    if (gi > g) return;
    int lo = 0, hi = n;
    while (lo < hi) {
        int mid = (lo + hi) >> 1;
        if (batch[mid] < gi) lo = mid + 1; else hi = mid;
    }
    gstart[gi] = lo;
}

// ---------------- fused tail: BN(layer2)+relu -> mean pool -> MLP head ----------------
__global__ __launch_bounds__(128) void k_tail(
        const float* __restrict__ h_pre, const int* __restrict__ gstart,
        const float* __restrict__ colsum, const float* __restrict__ colsumsq,
        float inv_n, const float* __restrict__ gamma, const float* __restrict__ beta,
        const float* __restrict__ W1, const float* __restrict__ b1,
        const float* __restrict__ W2, const float* __restrict__ b2,
        float* __restrict__ out) {
    __shared__ float s_a[HD], s_b[HD];
    __shared__ float2 red[128];
    __shared__ float p[HD], t[HD];
    const int gi = blockIdx.x;
    const int tid = threadIdx.x;

    {   // BN coefficients for layer 2
        float mean = colsum[tid] * inv_n;
        float var = colsumsq[tid] * inv_n - mean * mean;
        float rstd = 1.0f / sqrtf(var + EPS);
        float a = gamma[tid] * rstd;
        s_a[tid] = a;
        s_b[tid] = beta[tid] - mean * a;
    }
    __syncthreads();

    const int lane = tid & 63;
    const int half = tid >> 6;          // 0/1: alternate rows
    const float2* __restrict__ h2 = (const float2*)h_pre;
    const float2 a2 = make_float2(s_a[lane * 2], s_a[lane * 2 + 1]);
    const float2 b2v = make_float2(s_b[lane * 2], s_b[lane * 2 + 1]);
    int s = gstart[gi], e = gstart[gi + 1];
    float2 sum = make_float2(0.f, 0.f);
    for (int i = s + half; i < e; i += 2) {
        float2 v = h2[(size_t)i * 64 + lane];
        sum.x += fmaxf(fmaf(v.x, a2.x, b2v.x), 0.f);
        sum.y += fmaxf(fmaf(v.y, a2.y, b2v.y), 0.f);
    }
    red[tid] = sum;
    __syncthreads();
    if (half == 0) {
        float2 o = red[tid + 64];
        sum.x += o.x; sum.y += o.y;
        float inv = 1.0f / fmaxf((float)(e - s), 1.0f);
        p[lane * 2]     = sum.x * inv;
        p[lane * 2 + 1] = sum.y * inv;
    }
    __syncthreads();

    // head MLP
    float acc = b1[tid];
    #pragma unroll 8
    for (int k = 0; k < HD; ++k) acc = fmaf(p[k], W1[(size_t)k * HD + tid], acc);
    t[tid] = fmaxf(acc, 0.f);
    __syncthreads();
    if (tid < EMB) {
        float o = b2[tid];
        #pragma unroll 8
        for (int k = 0; k < HD; ++k) o = fmaf(t[k], W2[(size_t)k * EMB + tid], o);
        out[(size_t)gi * EMB + tid] = o;
    }
}

extern "C" void kernel_launch(void* const* d_in, const int* in_sizes, int n_in,
                              void* d_out, int out_size, void* d_ws, size_t ws_size,
                              hipStream_t stream) {
    const float* x     = (const float*)d_in[0];
    const int*   ei    = (const int*)d_in[1];
    const int*   batch = (const int*)d_in[2];
    const float* W_in  = (const float*)d_in[3];
    const float* b_in  = (const float*)d_in[4];
    const float* Ws    = (const float*)d_in[5];
    const float* bs    = (const float*)d_in[6];
    const float* gam   = (const float*)d_in[7];
    const float* bet   = (const float*)d_in[8];
    const float* W1    = (const float*)d_in[9];
    const float* b1    = (const float*)d_in[10];
    const float* W2    = (const float*)d_in[11];
    const float* b2    = (const float*)d_in[12];
    float* out = (float*)d_out;

    const int n = in_sizes[0] / HD;   // 100000
    const int e = in_sizes[1] / 2;    // 1600000
    const int g = out_size / EMB;     // 1024
    const float inv_n = 1.0f / (float)n;

    const int* esrc = ei;
    const int* edst = ei + e;

    // ---- workspace carve (256B aligned) ----
    char* w = (char*)d_ws;
    auto alloc = [&](size_t bytes) {
        char* p = w;
        w += (bytes + 255) & ~(size_t)255;
        return p;
    };
    float* hbuf             = (float*)alloc((size_t)n * HD * 4);
    unsigned short* hw      = (unsigned short*)alloc((size_t)n * HD * 2);  // bf16 gather table
    unsigned short* wtbuf   = (unsigned short*)alloc((size_t)4 * HD * HD * 2); // bf16 W^T x4
    int*   csr_src = (int*)alloc((size_t)e * 4);
    int*   deg     = (int*)alloc((size_t)n * 4);
    float* dinv    = (float*)alloc((size_t)n * 4);
    int*   rstart  = (int*)alloc((size_t)(n + 1) * 4);
    int*   cursor  = (int*)alloc((size_t)n * 4);
    int*   bsum    = (int*)alloc(512 * 4);
    float* csbuf   = (float*)alloc(3 * 256 * 4);   // per-layer colsum/colsumsq
    int*   gstart  = (int*)alloc((size_t)(g + 1) * 4);

    hipMemsetAsync(deg, 0, (size_t)n * 4, stream);
    hipMemsetAsync(csbuf, 0, 3 * 256 * 4, stream);

    const int eb = (e + 255) / 256;
    const int nb = (n + 255) / 256;

    k_wprep<<<512, 128, 0, stream>>>(W_in, Ws, wtbuf);
    k_hist<<<eb, 256, 0, stream>>>(edst, deg, e);
    k_dinv<<<nb, 256, 0, stream>>>(deg, dinv, n);
    k_scan_part<<<nb, 256, 0, stream>>>(deg, rstart, bsum, n);
    k_scan_mid<<<1, 512, 0, stream>>>(bsum, nb);
    k_scan_add<<<nb, 256, 0, stream>>>(rstart, cursor, bsum, n, e);
    k_scatter<<<eb, 256, 0, stream>>>(esrc, edst, cursor, csr_src, e);

    const int gb = (n + 127) / 128;
    // input projection: h = relu(x @ W_in + b_in)  (fp32 out)
    k_gemm<false, true, false><<<gb, 256, 0, stream>>>(
        x, wtbuf, b_in, nullptr, nullptr, nullptr, nullptr, 0.f, hbuf, n);

    const int ab = (n + 4 * NPB - 1) / (4 * NPB);
    for (int i = 0; i < 3; ++i) {
        float* cs = csbuf + (size_t)i * 256;           // this layer's stats (written by agg)
        if (i == 0)
            k_gemm<false, false, true><<<gb, 256, 0, stream>>>(
                hbuf, wtbuf + (size_t)(i + 1) * HD * HD, nullptr,
                nullptr, nullptr, nullptr, nullptr, 0.f, hw, n);
        else {
            float* csp = csbuf + (size_t)(i - 1) * 256; // previous layer's stats
            k_gemm<true, false, true><<<gb, 256, 0, stream>>>(
                hbuf, wtbuf + (size_t)(i + 1) * HD * HD, nullptr,
                gam + (size_t)(i - 1) * HD, bet + (size_t)(i - 1) * HD,
                csp, csp + HD, inv_n, hw, n);
        }
        k_agg<<<ab, 256, 0, stream>>>(hw, rstart, csr_src, dinv, bs + (size_t)i * HD,
                                      hbuf, cs, cs + HD, n);
    }

    k_gbounds<<<(g + 256) / 256, 256, 0, stream>>>(batch, gstart, n, g);
    float* cs2 = csbuf + 2 * 256;
    k_tail<<<g, 128, 0, stream>>>(hbuf, gstart, cs2, cs2 + HD, inv_n,
                                  gam + 2 * HD, bet + 2 * HD, W1, b1, W2, b2, out);
}